// Round 7
// baseline (406.373 us; speedup 1.0000x reference)
//
#include <hip/hip_runtime.h>
#include <math.h>

#define C 8192
#define D 1024
#define BATCH 1024
#define PM 0.95f
#define PMC 0.05f
// values pre-scaled by 8 before fp8 quant; dot comes out 64x too big.
// epilogue uses 10/64 = 0.15625 (exact in fp32).
#define INVT_SCALED 0.15625f

typedef unsigned char u8;
typedef __attribute__((ext_vector_type(16))) float f32x16;
typedef __attribute__((ext_vector_type(8))) int i32x8;

#define GLOBAL_AS(p) ((const __attribute__((address_space(1))) void*)(p))
#define LDS_AS(p) ((__attribute__((address_space(3))) void*)(p))

// ---------------------------------------------------------------------------
// EMA + fp8 quantize (r17 exact, verified). 512 blocks x 16 consecutive
// classes; LDS-staged quantize + block-cooperative coalesced writeback so
// each 128-B P8 line is written once, fully, from one block/L2. fp8 layout
// (512-B k-units):
//   element (row c, k) -> P8[(c>>5)*32768 + (k>>4)*512 + ((k>>3)&1)*256 + (c&31)*8 + (k&7)]
__global__ __launch_bounds__(256) void ema_split_kernel(const float* __restrict__ feat,
                                                        const int* __restrict__ labels,
                                                        const float* __restrict__ protos,
                                                        u8* __restrict__ P8,
                                                        float* __restrict__ rowsum,
                                                        float* __restrict__ out) {
    __shared__ int sl[BATCH];
    __shared__ unsigned int sq[128][16][2];   // [piece][class-in-block][half]  16 KB
    const int t = threadIdx.x, w = t >> 6, lane = t & 63;
    const int cb = blockIdx.x * 16;

    if (blockIdx.x < 32) rowsum[blockIdx.x * 256 + t] = 0.0f;
    if (blockIdx.x == 0 && t == 0) out[0] = 0.0f;

    for (int i = t; i < BATCH; i += 256) sl[i] = labels[i];
    __syncthreads();

    for (int i = 0; i < 4; ++i) {
        const int c = cb + w * 4 + i;

        float4 v[4];
        #pragma unroll
        for (int s = 0; s < 4; ++s)
            v[s] = *(const float4*)(protos + (size_t)c * D + s * 256 + lane * 4);

        for (int base = 0; base < BATCH; base += 64) {
            unsigned long long mask = __ballot(sl[base + lane] == c);
            while (mask) {
                const int b = __ffsll((long long)mask) - 1;
                mask &= mask - 1;
                const int idx = base + b;
                float ss = 0.0f;
                #pragma unroll
                for (int s = 0; s < 4; ++s) {
                    const float4 f = *(const float4*)(feat + (size_t)idx * D + s * 256 + lane * 4);
                    v[s].x = v[s].x * PM + f.x * PMC;
                    v[s].y = v[s].y * PM + f.y * PMC;
                    v[s].z = v[s].z * PM + f.z * PMC;
                    v[s].w = v[s].w * PM + f.w * PMC;
                    ss += v[s].x * v[s].x + v[s].y * v[s].y + v[s].z * v[s].z + v[s].w * v[s].w;
                }
                #pragma unroll
                for (int off = 32; off > 0; off >>= 1) ss += __shfl_xor(ss, off);
                const float inv = 1.0f / fmaxf(sqrtf(ss), 1e-12f);
                #pragma unroll
                for (int s = 0; s < 4; ++s) {
                    v[s].x *= inv; v[s].y *= inv; v[s].z *= inv; v[s].w *= inv;
                }
            }
        }

        // quantize into LDS staging: piece pp = s*32 + (lane>>1), half = lane&1
        #pragma unroll
        for (int s = 0; s < 4; ++s) {
            int p = __builtin_amdgcn_cvt_pk_fp8_f32(v[s].x * 8.0f, v[s].y * 8.0f, 0, false);
            p = __builtin_amdgcn_cvt_pk_fp8_f32(v[s].z * 8.0f, v[s].w * 8.0f, p, true);
            sq[s * 32 + (lane >> 1)][w * 4 + i][lane & 1] = (unsigned int)p;
        }
    }
    __syncthreads();

    // coalesced writeback: 1024 slots of 16 B (piece pp, class pair 2a,2a+1)
    u8* base = P8 + (size_t)(cb >> 5) * 32768 + (cb & 31) * 8;
    #pragma unroll
    for (int it = 0; it < 4; ++it) {
        const int slot = it * 256 + t;
        const int pp = slot >> 3, a = slot & 7;
        uint4 val;
        val.x = sq[pp][2 * a][0];     val.y = sq[pp][2 * a][1];
        val.z = sq[pp][2 * a + 1][0]; val.w = sq[pp][2 * a + 1][1];
        *(uint4*)(base + (pp >> 1) * 512 + (pp & 1) * 256 + a * 16) = val;
    }
}

// ---------------------------------------------------------------------------
// fp8 Gram via MX-scaled MFMA: mfma_scale_f32_32x32x64_f8f6f4, unit scales
// (E8M0 0x7F = 1.0), fp8 A/B formats (cbsz=blgp=0).
//
// r20 POST-MORTEM INSIGHT: non-scaled fp8 32x32x16 runs at BF16 rate
// (~37 cyc/instr) -> r13's K-loop was MFMA-ISSUE-bound (1184 cyc/chunk/CU
// vs LDS 770), so schedule/LDS surgery (r14-r19) could never help. The
// scaled instruction is 2.14x the rate (4686 vs 2190 TF measured) and
// consumes the SAME operand bytes -> ideal MFMA 31.7 -> 14.8 us; LDS
// (~20 us) becomes the bind.
//
// Operand layout (family pattern, verified instances 16x16x32 k=(l>>4)*8 and
// 32x32x16 k=(l>>5)*8): lane l -> row l&31, k = (l>>5)*32 + [0,32) contiguous.
// In our P8/LDS layout that is [h? odd-chunk buf : even-chunk buf] + tile +
// q*256 + (l&31)*8, q=0..3 -> the SAME 16 ds_read_b64 per 2 chunks as before,
// now feeding 4 scaled MFMAs (K=64) instead of 16 small ones.
//
// Skeleton = r16 (verified correct): 2-chunk periods, 5-buf ring, stages
// 2p+3,2p+4 into bufs consumed last period (one-barrier WAR), WAITV(2)
// certifies the next period's two chunks (never drains in-loop).
// Triangle cover bi<=bj (2080 blocks); diag blocks mask li>=lj ->
// rowsum == sum_neg. XCD swizzle: 260 blocks/XCD.
__global__ __launch_bounds__(256, 4) void gram8_kernel(const u8* __restrict__ P8,
                                                       float* __restrict__ rowsum) {
    __shared__ u8 lds[5][8192];      // per buf: A tiles 0..3 @ a*1024, B @ 4096+
    const int t = threadIdx.x, w = t >> 6, lane = t & 63;

    // swizzled block -> (bi, bj), bi <= bj, 128-row strips
    int mm = blockIdx.x >> 3;
    const int r = blockIdx.x & 7;
    int bi = 0;
    #pragma unroll
    for (int s = 0; s < 8; ++s) {
        const int strip = (s & 1) ? ((s >> 1) * 16 + 15 - r) : ((s >> 1) * 16 + r);
        const int n = 64 - strip;
        if (mm < n) { bi = strip; break; }
        mm -= n;
    }
    const int bj = bi + mm;
    const bool diag = (bi == bj);

    // per-wave staging: 2 glds x 1 KB per chunk (A tile w, B tile w)
    const u8* gsrcA = P8 + (size_t)(bi * 4 + w) * 32768 + lane * 16;
    const u8* gsrcB = P8 + (size_t)(bj * 4 + w) * 32768 + lane * 16;
    const int ldsA = w * 1024, ldsB = 4096 + w * 1024;

    const int qi = w >> 1, qj = w & 1;
    const int aT0 = qi * 2048, aT1 = qi * 2048 + 1024;          // wave's A tiles
    const int bT0 = 4096 + qj * 2048, bT1 = 4096 + qj * 2048 + 1024;
    const int cb8 = (lane & 31) * 8;

    f32x16 acc[2][2];
    #pragma unroll
    for (int a = 0; a < 2; ++a)
        #pragma unroll
        for (int b = 0; b < 2; ++b)
            #pragma unroll
            for (int e = 0; e < 16; ++e) acc[a][b][e] = 0.0f;

#define STAGE(KC, BUF)                                                         \
    __builtin_amdgcn_global_load_lds(GLOBAL_AS(gsrcA + (size_t)(KC) * 1024),   \
                                     LDS_AS(&lds[BUF][ldsA]), 16, 0, 0);       \
    __builtin_amdgcn_global_load_lds(GLOBAL_AS(gsrcB + (size_t)(KC) * 1024),   \
                                     LDS_AS(&lds[BUF][ldsB]), 16, 0, 0);

// load one K=64 operand (8 VGPRs) for tile at byte offset TB:
// lane half h reads from the h-selected chunk buffer (k = h*32 + [0,32))
#define LD8(DST, HB, TB)                                                       \
    {                                                                          \
        long* P_ = (long*)&(DST);                                              \
        P_[0] = *(const long*)((HB) + (TB) + cb8);                             \
        P_[1] = *(const long*)((HB) + (TB) + cb8 + 256);                       \
        P_[2] = *(const long*)((HB) + (TB) + cb8 + 512);                       \
        P_[3] = *(const long*)((HB) + (TB) + cb8 + 768);                       \
    }

// consume 2 chunks (K=64) from bufs C0 (k 0-31) / C1 (k 32-63): 16 b64 + 4 MFMA
#define CHUNK2(C0, C1)                                                         \
    {                                                                          \
        const u8* hb = (lane & 32) ? &lds[C1][0] : &lds[C0][0];                \
        i32x8 va0, va1, vb0, vb1;                                              \
        LD8(va0, hb, aT0); LD8(va1, hb, aT1);                                  \
        LD8(vb0, hb, bT0); LD8(vb1, hb, bT1);                                  \
        acc[0][0] = __builtin_amdgcn_mfma_scale_f32_32x32x64_f8f6f4(           \
            va0, vb0, acc[0][0], 0, 0, 0, 0x7F7F7F7F, 0, 0x7F7F7F7F);          \
        acc[0][1] = __builtin_amdgcn_mfma_scale_f32_32x32x64_f8f6f4(           \
            va0, vb1, acc[0][1], 0, 0, 0, 0x7F7F7F7F, 0, 0x7F7F7F7F);          \
        acc[1][0] = __builtin_amdgcn_mfma_scale_f32_32x32x64_f8f6f4(           \
            va1, vb0, acc[1][0], 0, 0, 0, 0x7F7F7F7F, 0, 0x7F7F7F7F);          \
        acc[1][1] = __builtin_amdgcn_mfma_scale_f32_32x32x64_f8f6f4(           \
            va1, vb1, acc[1][1], 0, 0, 0, 0x7F7F7F7F, 0, 0x7F7F7F7F);          \
    }

#define WAITV(N) asm volatile("s_waitcnt vmcnt(" #N ")" ::: "memory")

    // prologue: stage chunks 0..2 into bufs 0..2 (6 glds outstanding/wave)
    STAGE(0, 0); STAGE(1, 1); STAGE(2, 2);
    WAITV(2);                                // chunks 0,1 resident
    __builtin_amdgcn_s_barrier();

    // main loop: period p consumes chunks 2p,2p+1; stages 2p+3,2p+4.
    int c0 = 0;
    for (int p = 0; p < 14; ++p) {
        const int c1  = (c0 == 4) ? 0 : c0 + 1;
        const int nc0 = (c1 == 4) ? 0 : c1 + 1;       // buf of chunk 2p+2
        const int s0  = (nc0 == 4) ? 0 : nc0 + 1;     // (c0+3)%5: held 2p-2
        const int s1  = (s0 == 4) ? 0 : s0 + 1;       // (c0+4)%5: held 2p-1
        STAGE(2 * p + 3, s0);
        STAGE(2 * p + 4, s1);
        CHUNK2(c0, c1);
        WAITV(2);                            // certifies chunks 2p+2, 2p+3
        __builtin_amdgcn_s_barrier();
        c0 = nc0;
    }
    // peeled period 14: consume 28(buf3),29(buf4); stage 31 -> buf1 (held 26)
    STAGE(31, 1);
    CHUNK2(3, 4);
    WAITV(0);                                // chunks 30,31 resident
    __builtin_amdgcn_s_barrier();
    // peeled period 15: consume 30(buf0), 31(buf1)
    CHUNK2(0, 1);

    // epilogue: exp(acc*10/64), diag-block triangle mask, row/col partials.
    // C layout (32x32, shape-determined): col = lane&31,
    // row = (reg&3) + 8*(reg>>2) + 4*(lane>>5)
    __syncthreads();                         // K-loop fully done; lds reusable
    float* rpart = (float*)&lds[0][0];
    float* cpart = (float*)&lds[0][512];
    if (t < 128) { rpart[t] = 0.0f; cpart[t] = 0.0f; }
    __syncthreads();
    const int half = lane >> 5, col = lane & 31;
    float csum[2] = {0.0f, 0.0f};
    #pragma unroll
    for (int ti = 0; ti < 2; ++ti) {
        float rs[16];
        #pragma unroll
        for (int reg = 0; reg < 16; ++reg) rs[reg] = 0.0f;
        #pragma unroll
        for (int tj = 0; tj < 2; ++tj) {
            const int lj = qj * 64 + tj * 32 + col;
            #pragma unroll
            for (int reg = 0; reg < 16; ++reg) {
                const int li = qi * 64 + ti * 32 + (reg & 3) + 8 * (reg >> 2) + 4 * half;
                float e = __expf(acc[ti][tj][reg] * INVT_SCALED);
                if (diag && li >= lj) e = 0.0f;      // bi<bj blocks: always li<lj globally
                rs[reg] += e;
                csum[tj] += e;
            }
        }
        #pragma unroll
        for (int reg = 0; reg < 16; ++reg) {
            float v = rs[reg];
            v += __shfl_xor(v, 1); v += __shfl_xor(v, 2); v += __shfl_xor(v, 4);
            v += __shfl_xor(v, 8); v += __shfl_xor(v, 16);
            if (col == 0)
                atomicAdd(&rpart[qi * 64 + ti * 32 + (reg & 3) + 8 * (reg >> 2) + 4 * half], v);
        }
    }
    #pragma unroll
    for (int tj = 0; tj < 2; ++tj) {
        float v = csum[tj];
        v += __shfl_xor(v, 32);
        if (half == 0) atomicAdd(&cpart[qj * 64 + tj * 32 + col], v);
    }
    __syncthreads();
    if (t < 128) atomicAdd(&rowsum[bi * 128 + t], rpart[t]);
    else         atomicAdd(&rowsum[bj * 128 + (t - 128)], cpart[t - 128]);
}

// ---------------------------------------------------------------------------
// rowsum == sum_neg (diag + lower triangle excluded in gram)
__global__ __launch_bounds__(256) void final2_kernel(const float* __restrict__ rowsum,
                                                     float* __restrict__ out) {
    __shared__ float red[4];
    const int t = threadIdx.x;
    const int i = blockIdx.x * 256 + t;
    float v = logf(rowsum[i] * (1.0f / (float)(C - 1)));
    #pragma unroll
    for (int off = 32; off > 0; off >>= 1) v += __shfl_down(v, off);
    if ((t & 63) == 0) red[t >> 6] = v;
    __syncthreads();
    if (t == 0)
        atomicAdd(out, (red[0] + red[1] + red[2] + red[3]) * (1.0f / (float)C));
}

// ---------------------------------------------------------------------------
extern "C" void kernel_launch(void* const* d_in, const int* in_sizes, int n_in,
                              void* d_out, int out_size, void* d_ws, size_t ws_size,
                              hipStream_t stream) {
    const float* feat = (const float*)d_in[0];
    const int* labels = (const int*)d_in[1];
    const float* protos = (const float*)d_in[2];
    float* out = (float*)d_out;
    float* rowsum = (float*)d_ws;               // 32 KB
    u8* P8 = (u8*)((char*)d_ws + 32768);        // 8 MiB packed fp8 protos

    ema_split_kernel<<<C / 16, 256, 0, stream>>>(feat, labels, protos, P8, rowsum, out);
    gram8_kernel<<<2080, 256, 0, stream>>>(P8, rowsum);
    final2_kernel<<<C / 256, 256, 0, stream>>>(rowsum, out);
}

// Round 8
// 367.720 us; speedup vs baseline: 1.1051x; 1.1051x over previous
//
#include <hip/hip_runtime.h>
#include <math.h>

#define C 8192
#define D 1024
#define BATCH 1024
#define PM 0.95f
#define PMC 0.05f
// values pre-scaled by 8 before fp8 quant; dot comes out 64x too big.
// epilogue uses 10/64 = 0.15625 (exact in fp32).
#define INVT_SCALED 0.15625f

typedef unsigned char u8;
typedef __attribute__((ext_vector_type(16))) float f32x16;
typedef __attribute__((ext_vector_type(8))) int i32x8;

#define GLOBAL_AS(p) ((const __attribute__((address_space(1))) void*)(p))
#define LDS_AS(p) ((__attribute__((address_space(3))) void*)(p))

// ---------------------------------------------------------------------------
// EMA + fp8 quantize (r17 exact, verified). 512 blocks x 16 consecutive
// classes; LDS-staged quantize + block-cooperative coalesced writeback so
// each 128-B P8 line is written once, fully, from one block/L2. fp8 layout
// (512-B k-units):
//   element (row c, k) -> P8[(c>>5)*32768 + (k>>4)*512 + ((k>>3)&1)*256 + (c&31)*8 + (k&7)]
__global__ __launch_bounds__(256) void ema_split_kernel(const float* __restrict__ feat,
                                                        const int* __restrict__ labels,
                                                        const float* __restrict__ protos,
                                                        u8* __restrict__ P8,
                                                        float* __restrict__ rowsum,
                                                        float* __restrict__ out) {
    __shared__ int sl[BATCH];
    __shared__ unsigned int sq[128][16][2];   // [piece][class-in-block][half]  16 KB
    const int t = threadIdx.x, w = t >> 6, lane = t & 63;
    const int cb = blockIdx.x * 16;

    if (blockIdx.x < 32) rowsum[blockIdx.x * 256 + t] = 0.0f;
    if (blockIdx.x == 0 && t == 0) out[0] = 0.0f;

    for (int i = t; i < BATCH; i += 256) sl[i] = labels[i];
    __syncthreads();

    for (int i = 0; i < 4; ++i) {
        const int c = cb + w * 4 + i;

        float4 v[4];
        #pragma unroll
        for (int s = 0; s < 4; ++s)
            v[s] = *(const float4*)(protos + (size_t)c * D + s * 256 + lane * 4);

        for (int base = 0; base < BATCH; base += 64) {
            unsigned long long mask = __ballot(sl[base + lane] == c);
            while (mask) {
                const int b = __ffsll((long long)mask) - 1;
                mask &= mask - 1;
                const int idx = base + b;
                float ss = 0.0f;
                #pragma unroll
                for (int s = 0; s < 4; ++s) {
                    const float4 f = *(const float4*)(feat + (size_t)idx * D + s * 256 + lane * 4);
                    v[s].x = v[s].x * PM + f.x * PMC;
                    v[s].y = v[s].y * PM + f.y * PMC;
                    v[s].z = v[s].z * PM + f.z * PMC;
                    v[s].w = v[s].w * PM + f.w * PMC;
                    ss += v[s].x * v[s].x + v[s].y * v[s].y + v[s].z * v[s].z + v[s].w * v[s].w;
                }
                #pragma unroll
                for (int off = 32; off > 0; off >>= 1) ss += __shfl_xor(ss, off);
                const float inv = 1.0f / fmaxf(sqrtf(ss), 1e-12f);
                #pragma unroll
                for (int s = 0; s < 4; ++s) {
                    v[s].x *= inv; v[s].y *= inv; v[s].z *= inv; v[s].w *= inv;
                }
            }
        }

        // quantize into LDS staging: piece pp = s*32 + (lane>>1), half = lane&1
        #pragma unroll
        for (int s = 0; s < 4; ++s) {
            int p = __builtin_amdgcn_cvt_pk_fp8_f32(v[s].x * 8.0f, v[s].y * 8.0f, 0, false);
            p = __builtin_amdgcn_cvt_pk_fp8_f32(v[s].z * 8.0f, v[s].w * 8.0f, p, true);
            sq[s * 32 + (lane >> 1)][w * 4 + i][lane & 1] = (unsigned int)p;
        }
    }
    __syncthreads();

    // coalesced writeback: 1024 slots of 16 B (piece pp, class pair 2a,2a+1)
    u8* base = P8 + (size_t)(cb >> 5) * 32768 + (cb & 31) * 8;
    #pragma unroll
    for (int it = 0; it < 4; ++it) {
        const int slot = it * 256 + t;
        const int pp = slot >> 3, a = slot & 7;
        uint4 val;
        val.x = sq[pp][2 * a][0];     val.y = sq[pp][2 * a][1];
        val.z = sq[pp][2 * a + 1][0]; val.w = sq[pp][2 * a + 1][1];
        *(uint4*)(base + (pp >> 1) * 512 + (pp & 1) * 256 + a * 16) = val;
    }
}

// ---------------------------------------------------------------------------
// fp8 Gram via MX-scaled MFMA: mfma_scale_f32_32x32x64_f8f6f4, unit scales
// (E8M0 0x7F = 1.0), fp8 A/B formats (cbsz=blgp=0). Layout + semantics
// HW-VERIFIED in r20 (passed, absmax 0): lane l -> row l&31,
// k = (l>>5)*32 + [0,32) contiguous; in our P8/LDS layout = half-selected
// chunk buffer + tile + q*256 + (l&31)*8, q=0..3 (16 ds_read_b64 / 2 chunks,
// feeding 4 K=64 MFMAs).
//
// r21 FIX: r20's __launch_bounds__(256,4) capped the unified reg file at
// 128/wave; acc(64) + operand tuples(32, 8-reg-aligned) + addressing spilled
// the accumulators to scratch -> WRITE_SIZE 684 MB, 334 us. One change:
// min-waves 4 -> 3 (budget 170, need ~130; occupancy 3 blocks/CU, LDS
// 3x40=120 <= 160 KB not binding; 12 waves/CU suffices for the 5-deep ring,
// proven by r13's counted-vmcnt discipline).
//
// Skeleton = r16 (verified): 2-chunk periods, 5-buf ring, stages 2p+3,2p+4
// into bufs consumed last period (one-barrier WAR), WAITV(2) certifies the
// next period's two chunks (never drains in-loop).
// Triangle cover bi<=bj (2080 blocks); diag blocks mask li>=lj ->
// rowsum == sum_neg. XCD swizzle: 260 blocks/XCD.
__global__ __launch_bounds__(256, 3) void gram8_kernel(const u8* __restrict__ P8,
                                                       float* __restrict__ rowsum) {
    __shared__ u8 lds[5][8192];      // per buf: A tiles 0..3 @ a*1024, B @ 4096+
    const int t = threadIdx.x, w = t >> 6, lane = t & 63;

    // swizzled block -> (bi, bj), bi <= bj, 128-row strips
    int mm = blockIdx.x >> 3;
    const int r = blockIdx.x & 7;
    int bi = 0;
    #pragma unroll
    for (int s = 0; s < 8; ++s) {
        const int strip = (s & 1) ? ((s >> 1) * 16 + 15 - r) : ((s >> 1) * 16 + r);
        const int n = 64 - strip;
        if (mm < n) { bi = strip; break; }
        mm -= n;
    }
    const int bj = bi + mm;
    const bool diag = (bi == bj);

    // per-wave staging: 2 glds x 1 KB per chunk (A tile w, B tile w)
    const u8* gsrcA = P8 + (size_t)(bi * 4 + w) * 32768 + lane * 16;
    const u8* gsrcB = P8 + (size_t)(bj * 4 + w) * 32768 + lane * 16;
    const int ldsA = w * 1024, ldsB = 4096 + w * 1024;

    const int qi = w >> 1, qj = w & 1;
    const int aT0 = qi * 2048, aT1 = qi * 2048 + 1024;          // wave's A tiles
    const int bT0 = 4096 + qj * 2048, bT1 = 4096 + qj * 2048 + 1024;
    const int cb8 = (lane & 31) * 8;

    f32x16 acc[2][2];
    #pragma unroll
    for (int a = 0; a < 2; ++a)
        #pragma unroll
        for (int b = 0; b < 2; ++b)
            #pragma unroll
            for (int e = 0; e < 16; ++e) acc[a][b][e] = 0.0f;

#define STAGE(KC, BUF)                                                         \
    __builtin_amdgcn_global_load_lds(GLOBAL_AS(gsrcA + (size_t)(KC) * 1024),   \
                                     LDS_AS(&lds[BUF][ldsA]), 16, 0, 0);       \
    __builtin_amdgcn_global_load_lds(GLOBAL_AS(gsrcB + (size_t)(KC) * 1024),   \
                                     LDS_AS(&lds[BUF][ldsB]), 16, 0, 0);

// load one K=64 operand (8 VGPRs) for tile at byte offset TB:
// lane half h reads from the h-selected chunk buffer (k = h*32 + [0,32))
#define LD8(DST, HB, TB)                                                       \
    {                                                                          \
        long* P_ = (long*)&(DST);                                              \
        P_[0] = *(const long*)((HB) + (TB) + cb8);                             \
        P_[1] = *(const long*)((HB) + (TB) + cb8 + 256);                       \
        P_[2] = *(const long*)((HB) + (TB) + cb8 + 512);                       \
        P_[3] = *(const long*)((HB) + (TB) + cb8 + 768);                       \
    }

// consume 2 chunks (K=64) from bufs C0 (k 0-31) / C1 (k 32-63): 16 b64 + 4 MFMA
#define CHUNK2(C0, C1)                                                         \
    {                                                                          \
        const u8* hb = (lane & 32) ? &lds[C1][0] : &lds[C0][0];                \
        i32x8 va0, va1, vb0, vb1;                                              \
        LD8(va0, hb, aT0); LD8(va1, hb, aT1);                                  \
        LD8(vb0, hb, bT0); LD8(vb1, hb, bT1);                                  \
        acc[0][0] = __builtin_amdgcn_mfma_scale_f32_32x32x64_f8f6f4(           \
            va0, vb0, acc[0][0], 0, 0, 0, 0x7F7F7F7F, 0, 0x7F7F7F7F);          \
        acc[0][1] = __builtin_amdgcn_mfma_scale_f32_32x32x64_f8f6f4(           \
            va0, vb1, acc[0][1], 0, 0, 0, 0x7F7F7F7F, 0, 0x7F7F7F7F);          \
        acc[1][0] = __builtin_amdgcn_mfma_scale_f32_32x32x64_f8f6f4(           \
            va1, vb0, acc[1][0], 0, 0, 0, 0x7F7F7F7F, 0, 0x7F7F7F7F);          \
        acc[1][1] = __builtin_amdgcn_mfma_scale_f32_32x32x64_f8f6f4(           \
            va1, vb1, acc[1][1], 0, 0, 0, 0x7F7F7F7F, 0, 0x7F7F7F7F);          \
    }

#define WAITV(N) asm volatile("s_waitcnt vmcnt(" #N ")" ::: "memory")

    // prologue: stage chunks 0..2 into bufs 0..2 (6 glds outstanding/wave)
    STAGE(0, 0); STAGE(1, 1); STAGE(2, 2);
    WAITV(2);                                // chunks 0,1 resident
    __builtin_amdgcn_s_barrier();

    // main loop: period p consumes chunks 2p,2p+1; stages 2p+3,2p+4.
    int c0 = 0;
    for (int p = 0; p < 14; ++p) {
        const int c1  = (c0 == 4) ? 0 : c0 + 1;
        const int nc0 = (c1 == 4) ? 0 : c1 + 1;       // buf of chunk 2p+2
        const int s0  = (nc0 == 4) ? 0 : nc0 + 1;     // (c0+3)%5: held 2p-2
        const int s1  = (s0 == 4) ? 0 : s0 + 1;       // (c0+4)%5: held 2p-1
        STAGE(2 * p + 3, s0);
        STAGE(2 * p + 4, s1);
        CHUNK2(c0, c1);
        WAITV(2);                            // certifies chunks 2p+2, 2p+3
        __builtin_amdgcn_s_barrier();
        c0 = nc0;
    }
    // peeled period 14: consume 28(buf3),29(buf4); stage 31 -> buf1 (held 26)
    STAGE(31, 1);
    CHUNK2(3, 4);
    WAITV(0);                                // chunks 30,31 resident
    __builtin_amdgcn_s_barrier();
    // peeled period 15: consume 30(buf0), 31(buf1)
    CHUNK2(0, 1);

    // epilogue: exp(acc*10/64), diag-block triangle mask, row/col partials.
    // C layout (32x32, shape-determined): col = lane&31,
    // row = (reg&3) + 8*(reg>>2) + 4*(lane>>5)
    __syncthreads();                         // K-loop fully done; lds reusable
    float* rpart = (float*)&lds[0][0];
    float* cpart = (float*)&lds[0][512];
    if (t < 128) { rpart[t] = 0.0f; cpart[t] = 0.0f; }
    __syncthreads();
    const int half = lane >> 5, col = lane & 31;
    float csum[2] = {0.0f, 0.0f};
    #pragma unroll
    for (int ti = 0; ti < 2; ++ti) {
        float rs[16];
        #pragma unroll
        for (int reg = 0; reg < 16; ++reg) rs[reg] = 0.0f;
        #pragma unroll
        for (int tj = 0; tj < 2; ++tj) {
            const int lj = qj * 64 + tj * 32 + col;
            #pragma unroll
            for (int reg = 0; reg < 16; ++reg) {
                const int li = qi * 64 + ti * 32 + (reg & 3) + 8 * (reg >> 2) + 4 * half;
                float e = __expf(acc[ti][tj][reg] * INVT_SCALED);
                if (diag && li >= lj) e = 0.0f;      // bi<bj blocks: always li<lj globally
                rs[reg] += e;
                csum[tj] += e;
            }
        }
        #pragma unroll
        for (int reg = 0; reg < 16; ++reg) {
            float v = rs[reg];
            v += __shfl_xor(v, 1); v += __shfl_xor(v, 2); v += __shfl_xor(v, 4);
            v += __shfl_xor(v, 8); v += __shfl_xor(v, 16);
            if (col == 0)
                atomicAdd(&rpart[qi * 64 + ti * 32 + (reg & 3) + 8 * (reg >> 2) + 4 * half], v);
        }
    }
    #pragma unroll
    for (int tj = 0; tj < 2; ++tj) {
        float v = csum[tj];
        v += __shfl_xor(v, 32);
        if (half == 0) atomicAdd(&cpart[qj * 64 + tj * 32 + col], v);
    }
    __syncthreads();
    if (t < 128) atomicAdd(&rowsum[bi * 128 + t], rpart[t]);
    else         atomicAdd(&rowsum[bj * 128 + (t - 128)], cpart[t - 128]);
}

// ---------------------------------------------------------------------------
// rowsum == sum_neg (diag + lower triangle excluded in gram)
__global__ __launch_bounds__(256) void final2_kernel(const float* __restrict__ rowsum,
                                                     float* __restrict__ out) {
    __shared__ float red[4];
    const int t = threadIdx.x;
    const int i = blockIdx.x * 256 + t;
    float v = logf(rowsum[i] * (1.0f / (float)(C - 1)));
    #pragma unroll
    for (int off = 32; off > 0; off >>= 1) v += __shfl_down(v, off);
    if ((t & 63) == 0) red[t >> 6] = v;
    __syncthreads();
    if (t == 0)
        atomicAdd(out, (red[0] + red[1] + red[2] + red[3]) * (1.0f / (float)C));
}

// ---------------------------------------------------------------------------
extern "C" void kernel_launch(void* const* d_in, const int* in_sizes, int n_in,
                              void* d_out, int out_size, void* d_ws, size_t ws_size,
                              hipStream_t stream) {
    const float* feat = (const float*)d_in[0];
    const int* labels = (const int*)d_in[1];
    const float* protos = (const float*)d_in[2];
    float* out = (float*)d_out;
    float* rowsum = (float*)d_ws;               // 32 KB
    u8* P8 = (u8*)((char*)d_ws + 32768);        // 8 MiB packed fp8 protos

    ema_split_kernel<<<C / 16, 256, 0, stream>>>(feat, labels, protos, P8, rowsum, out);
    gram8_kernel<<<2080, 256, 0, stream>>>(P8, rowsum);
    final2_kernel<<<C / 256, 256, 0, stream>>>(rowsum, out);
}

// Round 9
// 367.459 us; speedup vs baseline: 1.1059x; 1.0007x over previous
//
#include <hip/hip_runtime.h>
#include <math.h>

#define C 8192
#define D 1024
#define BATCH 1024
#define PM 0.95f
#define PMC 0.05f
// values pre-scaled by 8 before fp8 quant; dot comes out 64x too big.
// epilogue uses 10/64 = 0.15625 (exact in fp32).
#define INVT_SCALED 0.15625f

typedef unsigned char u8;
typedef __attribute__((ext_vector_type(16))) float f32x16;
typedef __attribute__((ext_vector_type(8))) int i32x8;
typedef __attribute__((ext_vector_type(4))) int i32x4;
typedef __attribute__((ext_vector_type(2))) int i32x2;

#define GLOBAL_AS(p) ((const __attribute__((address_space(1))) void*)(p))
#define LDS_AS(p) ((__attribute__((address_space(3))) void*)(p))

// ---------------------------------------------------------------------------
// EMA + fp8 quantize (r17 exact, verified). 512 blocks x 16 consecutive
// classes; LDS-staged quantize + block-cooperative coalesced writeback so
// each 128-B P8 line is written once, fully, from one block/L2. fp8 layout
// (512-B k-units):
//   element (row c, k) -> P8[(c>>5)*32768 + (k>>4)*512 + ((k>>3)&1)*256 + (c&31)*8 + (k&7)]
__global__ __launch_bounds__(256) void ema_split_kernel(const float* __restrict__ feat,
                                                        const int* __restrict__ labels,
                                                        const float* __restrict__ protos,
                                                        u8* __restrict__ P8,
                                                        float* __restrict__ rowsum,
                                                        float* __restrict__ out) {
    __shared__ int sl[BATCH];
    __shared__ unsigned int sq[128][16][2];   // [piece][class-in-block][half]  16 KB
    const int t = threadIdx.x, w = t >> 6, lane = t & 63;
    const int cb = blockIdx.x * 16;

    if (blockIdx.x < 32) rowsum[blockIdx.x * 256 + t] = 0.0f;
    if (blockIdx.x == 0 && t == 0) out[0] = 0.0f;

    for (int i = t; i < BATCH; i += 256) sl[i] = labels[i];
    __syncthreads();

    for (int i = 0; i < 4; ++i) {
        const int c = cb + w * 4 + i;

        float4 v[4];
        #pragma unroll
        for (int s = 0; s < 4; ++s)
            v[s] = *(const float4*)(protos + (size_t)c * D + s * 256 + lane * 4);

        for (int base = 0; base < BATCH; base += 64) {
            unsigned long long mask = __ballot(sl[base + lane] == c);
            while (mask) {
                const int b = __ffsll((long long)mask) - 1;
                mask &= mask - 1;
                const int idx = base + b;
                float ss = 0.0f;
                #pragma unroll
                for (int s = 0; s < 4; ++s) {
                    const float4 f = *(const float4*)(feat + (size_t)idx * D + s * 256 + lane * 4);
                    v[s].x = v[s].x * PM + f.x * PMC;
                    v[s].y = v[s].y * PM + f.y * PMC;
                    v[s].z = v[s].z * PM + f.z * PMC;
                    v[s].w = v[s].w * PM + f.w * PMC;
                    ss += v[s].x * v[s].x + v[s].y * v[s].y + v[s].z * v[s].z + v[s].w * v[s].w;
                }
                #pragma unroll
                for (int off = 32; off > 0; off >>= 1) ss += __shfl_xor(ss, off);
                const float inv = 1.0f / fmaxf(sqrtf(ss), 1e-12f);
                #pragma unroll
                for (int s = 0; s < 4; ++s) {
                    v[s].x *= inv; v[s].y *= inv; v[s].z *= inv; v[s].w *= inv;
                }
            }
        }

        // quantize into LDS staging: piece pp = s*32 + (lane>>1), half = lane&1
        #pragma unroll
        for (int s = 0; s < 4; ++s) {
            int p = __builtin_amdgcn_cvt_pk_fp8_f32(v[s].x * 8.0f, v[s].y * 8.0f, 0, false);
            p = __builtin_amdgcn_cvt_pk_fp8_f32(v[s].z * 8.0f, v[s].w * 8.0f, p, true);
            sq[s * 32 + (lane >> 1)][w * 4 + i][lane & 1] = (unsigned int)p;
        }
    }
    __syncthreads();

    // coalesced writeback: 1024 slots of 16 B (piece pp, class pair 2a,2a+1)
    u8* base = P8 + (size_t)(cb >> 5) * 32768 + (cb & 31) * 8;
    #pragma unroll
    for (int it = 0; it < 4; ++it) {
        const int slot = it * 256 + t;
        const int pp = slot >> 3, a = slot & 7;
        uint4 val;
        val.x = sq[pp][2 * a][0];     val.y = sq[pp][2 * a][1];
        val.z = sq[pp][2 * a + 1][0]; val.w = sq[pp][2 * a + 1][1];
        *(uint4*)(base + (pp >> 1) * 512 + (pp & 1) * 256 + a * 16) = val;
    }
}

// ---------------------------------------------------------------------------
// fp8 Gram via MX-scaled MFMA: mfma_scale_f32_32x32x64_f8f6f4, unit scales
// (E8M0 0x7F = 1.0), fp8 A/B formats (cbsz=blgp=0). Layout + semantics
// HW-VERIFIED (r20/r21 passed, absmax 0): lane l -> row l&31,
// k = (l>>5)*32 + [0,32) contiguous; in our P8/LDS layout = half-selected
// chunk buffer + tile + q*256 + (l&31)*8, q=0..3.
//
// r22 FIX: r20/r21's 334/293-us disaster was NOT a register-budget spill
// (r21 raised the budget to 170, WRITE_SIZE stayed 601 MB) -- it was
// ADDRESS-TAKEN VECTOR ALLOCAS: LD8 built each i32x8 by storing through a
// long* alias, defeating SROA; the operand tuples lived in scratch with
// buffer_load/store around every MFMA (~512 KB/block, = observed traffic).
// Fix: assemble operands in pure SSA -- four i32x2 ds_read_b64 results
// combined with __builtin_shufflevector. No address ever taken.
//
// Skeleton = r16 (verified): 2-chunk periods, 5-buf ring, stages 2p+3,2p+4
// into bufs consumed last period (one-barrier WAR), WAITV(2) certifies the
// next period's two chunks (never drains in-loop). launch_bounds (256,3):
// ~130 regs fits 170 budget; 3 blocks/CU, LDS 120 KB, 12 waves/CU.
// Triangle cover bi<=bj (2080 blocks); diag blocks mask li>=lj ->
// rowsum == sum_neg. XCD swizzle: 260 blocks/XCD.
__global__ __launch_bounds__(256, 3) void gram8_kernel(const u8* __restrict__ P8,
                                                       float* __restrict__ rowsum) {
    __shared__ u8 lds[5][8192];      // per buf: A tiles 0..3 @ a*1024, B @ 4096+
    const int t = threadIdx.x, w = t >> 6, lane = t & 63;

    // swizzled block -> (bi, bj), bi <= bj, 128-row strips
    int mm = blockIdx.x >> 3;
    const int r = blockIdx.x & 7;
    int bi = 0;
    #pragma unroll
    for (int s = 0; s < 8; ++s) {
        const int strip = (s & 1) ? ((s >> 1) * 16 + 15 - r) : ((s >> 1) * 16 + r);
        const int n = 64 - strip;
        if (mm < n) { bi = strip; break; }
        mm -= n;
    }
    const int bj = bi + mm;
    const bool diag = (bi == bj);

    // per-wave staging: 2 glds x 1 KB per chunk (A tile w, B tile w)
    const u8* gsrcA = P8 + (size_t)(bi * 4 + w) * 32768 + lane * 16;
    const u8* gsrcB = P8 + (size_t)(bj * 4 + w) * 32768 + lane * 16;
    const int ldsA = w * 1024, ldsB = 4096 + w * 1024;

    const int qi = w >> 1, qj = w & 1;
    const int aT0 = qi * 2048, aT1 = qi * 2048 + 1024;          // wave's A tiles
    const int bT0 = 4096 + qj * 2048, bT1 = 4096 + qj * 2048 + 1024;
    const int cb8 = (lane & 31) * 8;

    f32x16 acc[2][2];
    #pragma unroll
    for (int a = 0; a < 2; ++a)
        #pragma unroll
        for (int b = 0; b < 2; ++b)
            #pragma unroll
            for (int e = 0; e < 16; ++e) acc[a][b][e] = 0.0f;

#define STAGE(KC, BUF)                                                         \
    __builtin_amdgcn_global_load_lds(GLOBAL_AS(gsrcA + (size_t)(KC) * 1024),   \
                                     LDS_AS(&lds[BUF][ldsA]), 16, 0, 0);       \
    __builtin_amdgcn_global_load_lds(GLOBAL_AS(gsrcB + (size_t)(KC) * 1024),   \
                                     LDS_AS(&lds[BUF][ldsB]), 16, 0, 0);

// SSA operand assembly: four ds_read_b64 -> shufflevector -> i32x8.
// No address taken; stays in registers.
#define LD8(DST, HB, TB)                                                       \
    {                                                                          \
        i32x2 q0_ = *(const i32x2*)((HB) + (TB) + cb8);                        \
        i32x2 q1_ = *(const i32x2*)((HB) + (TB) + cb8 + 256);                  \
        i32x2 q2_ = *(const i32x2*)((HB) + (TB) + cb8 + 512);                  \
        i32x2 q3_ = *(const i32x2*)((HB) + (TB) + cb8 + 768);                  \
        i32x4 lo_ = __builtin_shufflevector(q0_, q1_, 0, 1, 2, 3);             \
        i32x4 hi_ = __builtin_shufflevector(q2_, q3_, 0, 1, 2, 3);             \
        DST = __builtin_shufflevector(lo_, hi_, 0, 1, 2, 3, 4, 5, 6, 7);       \
    }

// consume 2 chunks (K=64) from bufs C0 (k 0-31) / C1 (k 32-63): 16 b64 + 4 MFMA
#define CHUNK2(C0, C1)                                                         \
    {                                                                          \
        const u8* hb = (lane & 32) ? &lds[C1][0] : &lds[C0][0];                \
        i32x8 va0, va1, vb0, vb1;                                              \
        LD8(va0, hb, aT0); LD8(va1, hb, aT1);                                  \
        LD8(vb0, hb, bT0); LD8(vb1, hb, bT1);                                  \
        acc[0][0] = __builtin_amdgcn_mfma_scale_f32_32x32x64_f8f6f4(           \
            va0, vb0, acc[0][0], 0, 0, 0, 0x7F7F7F7F, 0, 0x7F7F7F7F);          \
        acc[0][1] = __builtin_amdgcn_mfma_scale_f32_32x32x64_f8f6f4(           \
            va0, vb1, acc[0][1], 0, 0, 0, 0x7F7F7F7F, 0, 0x7F7F7F7F);          \
        acc[1][0] = __builtin_amdgcn_mfma_scale_f32_32x32x64_f8f6f4(           \
            va1, vb0, acc[1][0], 0, 0, 0, 0x7F7F7F7F, 0, 0x7F7F7F7F);          \
        acc[1][1] = __builtin_amdgcn_mfma_scale_f32_32x32x64_f8f6f4(           \
            va1, vb1, acc[1][1], 0, 0, 0, 0x7F7F7F7F, 0, 0x7F7F7F7F);          \
    }

#define WAITV(N) asm volatile("s_waitcnt vmcnt(" #N ")" ::: "memory")

    // prologue: stage chunks 0..2 into bufs 0..2 (6 glds outstanding/wave)
    STAGE(0, 0); STAGE(1, 1); STAGE(2, 2);
    WAITV(2);                                // chunks 0,1 resident
    __builtin_amdgcn_s_barrier();

    // main loop: period p consumes chunks 2p,2p+1; stages 2p+3,2p+4.
    int c0 = 0;
    for (int p = 0; p < 14; ++p) {
        const int c1  = (c0 == 4) ? 0 : c0 + 1;
        const int nc0 = (c1 == 4) ? 0 : c1 + 1;       // buf of chunk 2p+2
        const int s0  = (nc0 == 4) ? 0 : nc0 + 1;     // (c0+3)%5: held 2p-2
        const int s1  = (s0 == 4) ? 0 : s0 + 1;       // (c0+4)%5: held 2p-1
        STAGE(2 * p + 3, s0);
        STAGE(2 * p + 4, s1);
        CHUNK2(c0, c1);
        WAITV(2);                            // certifies chunks 2p+2, 2p+3
        __builtin_amdgcn_s_barrier();
        c0 = nc0;
    }
    // peeled period 14: consume 28(buf3),29(buf4); stage 31 -> buf1 (held 26)
    STAGE(31, 1);
    CHUNK2(3, 4);
    WAITV(0);                                // chunks 30,31 resident
    __builtin_amdgcn_s_barrier();
    // peeled period 15: consume 30(buf0), 31(buf1)
    CHUNK2(0, 1);

    // epilogue: exp(acc*10/64), diag-block triangle mask, row/col partials.
    // C layout (32x32, shape-determined): col = lane&31,
    // row = (reg&3) + 8*(reg>>2) + 4*(lane>>5)
    __syncthreads();                         // K-loop fully done; lds reusable
    float* rpart = (float*)&lds[0][0];
    float* cpart = (float*)&lds[0][512];
    if (t < 128) { rpart[t] = 0.0f; cpart[t] = 0.0f; }
    __syncthreads();
    const int half = lane >> 5, col = lane & 31;
    float csum[2] = {0.0f, 0.0f};
    #pragma unroll
    for (int ti = 0; ti < 2; ++ti) {
        float rs[16];
        #pragma unroll
        for (int reg = 0; reg < 16; ++reg) rs[reg] = 0.0f;
        #pragma unroll
        for (int tj = 0; tj < 2; ++tj) {
            const int lj = qj * 64 + tj * 32 + col;
            #pragma unroll
            for (int reg = 0; reg < 16; ++reg) {
                const int li = qi * 64 + ti * 32 + (reg & 3) + 8 * (reg >> 2) + 4 * half;
                float e = __expf(acc[ti][tj][reg] * INVT_SCALED);
                if (diag && li >= lj) e = 0.0f;      // bi<bj blocks: always li<lj globally
                rs[reg] += e;
                csum[tj] += e;
            }
        }
        #pragma unroll
        for (int reg = 0; reg < 16; ++reg) {
            float v = rs[reg];
            v += __shfl_xor(v, 1); v += __shfl_xor(v, 2); v += __shfl_xor(v, 4);
            v += __shfl_xor(v, 8); v += __shfl_xor(v, 16);
            if (col == 0)
                atomicAdd(&rpart[qi * 64 + ti * 32 + (reg & 3) + 8 * (reg >> 2) + 4 * half], v);
        }
    }
    #pragma unroll
    for (int tj = 0; tj < 2; ++tj) {
        float v = csum[tj];
        v += __shfl_xor(v, 32);
        if (half == 0) atomicAdd(&cpart[qj * 64 + tj * 32 + col], v);
    }
    __syncthreads();
    if (t < 128) atomicAdd(&rowsum[bi * 128 + t], rpart[t]);
    else         atomicAdd(&rowsum[bj * 128 + (t - 128)], cpart[t - 128]);
}

// ---------------------------------------------------------------------------
// rowsum == sum_neg (diag + lower triangle excluded in gram)
__global__ __launch_bounds__(256) void final2_kernel(const float* __restrict__ rowsum,
                                                     float* __restrict__ out) {
    __shared__ float red[4];
    const int t = threadIdx.x;
    const int i = blockIdx.x * 256 + t;
    float v = logf(rowsum[i] * (1.0f / (float)(C - 1)));
    #pragma unroll
    for (int off = 32; off > 0; off >>= 1) v += __shfl_down(v, off);
    if ((t & 63) == 0) red[t >> 6] = v;
    __syncthreads();
    if (t == 0)
        atomicAdd(out, (red[0] + red[1] + red[2] + red[3]) * (1.0f / (float)C));
}

// ---------------------------------------------------------------------------
extern "C" void kernel_launch(void* const* d_in, const int* in_sizes, int n_in,
                              void* d_out, int out_size, void* d_ws, size_t ws_size,
                              hipStream_t stream) {
    const float* feat = (const float*)d_in[0];
    const int* labels = (const int*)d_in[1];
    const float* protos = (const float*)d_in[2];
    float* out = (float*)d_out;
    float* rowsum = (float*)d_ws;               // 32 KB
    u8* P8 = (u8*)((char*)d_ws + 32768);        // 8 MiB packed fp8 protos

    ema_split_kernel<<<C / 16, 256, 0, stream>>>(feat, labels, protos, P8, rowsum, out);
    gram8_kernel<<<2080, 256, 0, stream>>>(P8, rowsum);
    final2_kernel<<<C / 256, 256, 0, stream>>>(rowsum, out);
}

// Round 10
// 146.756 us; speedup vs baseline: 2.7690x; 2.5039x over previous
//
#include <hip/hip_runtime.h>
#include <math.h>

#define C 8192
#define D 1024
#define BATCH 1024
#define PM 0.95f
#define PMC 0.05f
// int8 quant with scale 127 per side; dot comes out 16129x too big.
// epilogue uses 10/16129 (INVT = 1/TEMP = 10).
#define INVT_I8 (10.0f / 16129.0f)

typedef unsigned char u8;
typedef __attribute__((ext_vector_type(16))) int i32x16;
typedef __attribute__((ext_vector_type(4))) int i32x4;

#define GLOBAL_AS(p) ((const __attribute__((address_space(1))) void*)(p))
#define LDS_AS(p) ((__attribute__((address_space(3))) void*)(p))

// ---------------------------------------------------------------------------
// EMA + int8 quantize (r17 structure, verified; quant target changed fp8->i8).
// 512 blocks x 16 consecutive classes; LDS-staged quantize + block-cooperative
// coalesced writeback (each 128-B P8 line written once, fully, by one block).
// int8 layout (1-KB k-chunks per 32-row group, 16-B lane units for
// mfma_i32_32x32x32_i8, k = (l>>5)*16 + [0,16) contiguous):
//   element (row c, k) ->
//     P8[(c>>5)*32768 + (k>>5)*1024 + ((k>>4)&1)*512 + (c&31)*16 + (k&15)]
__global__ __launch_bounds__(256) void ema_split_kernel(const float* __restrict__ feat,
                                                        const int* __restrict__ labels,
                                                        const float* __restrict__ protos,
                                                        u8* __restrict__ P8,
                                                        float* __restrict__ rowsum,
                                                        float* __restrict__ out) {
    __shared__ int sl[BATCH];
    __shared__ unsigned int sq[64][16][4];    // [16B-piece][class-in-block][word]  16 KB
    const int t = threadIdx.x, w = t >> 6, lane = t & 63;
    const int cb = blockIdx.x * 16;

    if (blockIdx.x < 32) rowsum[blockIdx.x * 256 + t] = 0.0f;
    if (blockIdx.x == 0 && t == 0) out[0] = 0.0f;

    for (int i = t; i < BATCH; i += 256) sl[i] = labels[i];
    __syncthreads();

    for (int i = 0; i < 4; ++i) {
        const int c = cb + w * 4 + i;

        float4 v[4];
        #pragma unroll
        for (int s = 0; s < 4; ++s)
            v[s] = *(const float4*)(protos + (size_t)c * D + s * 256 + lane * 4);

        for (int base = 0; base < BATCH; base += 64) {
            unsigned long long mask = __ballot(sl[base + lane] == c);
            while (mask) {
                const int b = __ffsll((long long)mask) - 1;
                mask &= mask - 1;
                const int idx = base + b;
                float ss = 0.0f;
                #pragma unroll
                for (int s = 0; s < 4; ++s) {
                    const float4 f = *(const float4*)(feat + (size_t)idx * D + s * 256 + lane * 4);
                    v[s].x = v[s].x * PM + f.x * PMC;
                    v[s].y = v[s].y * PM + f.y * PMC;
                    v[s].z = v[s].z * PM + f.z * PMC;
                    v[s].w = v[s].w * PM + f.w * PMC;
                    ss += v[s].x * v[s].x + v[s].y * v[s].y + v[s].z * v[s].z + v[s].w * v[s].w;
                }
                #pragma unroll
                for (int off = 32; off > 0; off >>= 1) ss += __shfl_xor(ss, off);
                const float inv = 1.0f / fmaxf(sqrtf(ss), 1e-12f);
                #pragma unroll
                for (int s = 0; s < 4; ++s) {
                    v[s].x *= inv; v[s].y *= inv; v[s].z *= inv; v[s].w *= inv;
                }
            }
        }

        // int8 quantize into LDS staging: k0 = s*256 + lane*4;
        // piece = k0>>4 = s*16 + (lane>>2), word = lane&3. |v|<=1 -> |q|<=127.
        #pragma unroll
        for (int s = 0; s < 4; ++s) {
            const int qx = __float2int_rn(v[s].x * 127.0f);
            const int qy = __float2int_rn(v[s].y * 127.0f);
            const int qz = __float2int_rn(v[s].z * 127.0f);
            const int qw = __float2int_rn(v[s].w * 127.0f);
            const unsigned int pk = (qx & 0xFF) | ((qy & 0xFF) << 8) |
                                    ((qz & 0xFF) << 16) | ((unsigned int)(qw & 0xFF) << 24);
            sq[s * 16 + (lane >> 2)][w * 4 + i][lane & 3] = pk;
        }
    }
    __syncthreads();

    // coalesced writeback: 1024 slots of 16 B (piece pp16, class cls);
    // dst = base2 + (pp16>>1)*1024 + (pp16&1)*512 + cls*16
    u8* base2 = P8 + (size_t)(cb >> 5) * 32768 + (cb & 31) * 16;
    #pragma unroll
    for (int it = 0; it < 4; ++it) {
        const int slot = it * 256 + t;
        const int pp16 = slot >> 4, cls = slot & 15;
        uint4 val;
        val.x = sq[pp16][cls][0]; val.y = sq[pp16][cls][1];
        val.z = sq[pp16][cls][2]; val.w = sq[pp16][cls][3];
        *(uint4*)(base2 + (pp16 >> 1) * 1024 + (pp16 & 1) * 512 + cls * 16) = val;
    }
}

// ---------------------------------------------------------------------------
// int8 Gram, mfma_i32_32x32x32_i8 (NORMAL MFMA path -- r20-r22's mfma_scale
// builtin provably round-trips its C/D operand through scratch on this
// toolchain: WRITE_SIZE 601 MB invariant under operand-construction and
// launch-bounds changes; abandoned). i8 runs at 2x the non-scaled fp8 rate
// (4404 TOPS, 2x K per instr) -> r13's MFMA-issue bind (31.7 us ideal)
// halves to ~15.9 us. Structure = r13 VERBATIM: 2080 blocks + XCD strip
// swizzle, 5-buffer ring (40 KB, 4 blocks/CU), per-wave 2-gld staging,
// counted vmcnt (WAITV(4) at barrier kc certifies chunks kc+1, kc+2),
// cross-barrier register fragment prefetch, one-barrier WAR separation.
// Chunk = K=32 = 1 KB/group as before; inner loop is now 4 ds_read_b128 +
// 4 MFMAs per chunk (vs 8 b64 + 8 MFMAs): half the MFMA issue cycles, half
// the LDS instructions, same bytes. Fragment k-mapping (l>>5)*16+[0,16) is
// the family pattern whose K=64 form r20 HW-verified (absmax 0).
// Triangle cover bi<=bj; diag blocks mask li>=lj -> rowsum == sum_neg.
__global__ __launch_bounds__(256, 4) void gram8_kernel(const u8* __restrict__ P8,
                                                       float* __restrict__ rowsum) {
    __shared__ u8 lds[5][8192];      // per buf: A groups 0..3 @ g*1024, B @ 4096+
    const int t = threadIdx.x, w = t >> 6, lane = t & 63;

    // swizzled block -> (bi, bj), bi <= bj, 128-row strips
    int mm = blockIdx.x >> 3;
    const int r = blockIdx.x & 7;
    int bi = 0;
    #pragma unroll
    for (int s = 0; s < 8; ++s) {
        const int strip = (s & 1) ? ((s >> 1) * 16 + 15 - r) : ((s >> 1) * 16 + r);
        const int n = 64 - strip;
        if (mm < n) { bi = strip; break; }
        mm -= n;
    }
    const int bj = bi + mm;
    const bool diag = (bi == bj);

    // per-wave staging: 2 glds x 1 KB per chunk (A group w, B group w)
    const u8* gsrcA = P8 + (size_t)(bi * 4 + w) * 32768 + lane * 16;
    const u8* gsrcB = P8 + (size_t)(bj * 4 + w) * 32768 + lane * 16;
    const int ldsA = w * 1024, ldsB = 4096 + w * 1024;

    const int qi = w >> 1, qj = w & 1;
    const int aT0 = qi * 2048;                 // wave's A groups 2qi, 2qi+1
    const int bT0 = 4096 + qj * 2048;          // wave's B groups 2qj, 2qj+1
    const int alof = (lane >> 5) * 512 + (lane & 31) * 16;   // fragment addr in chunk

    i32x16 acc[2][2];
    #pragma unroll
    for (int a = 0; a < 2; ++a)
        #pragma unroll
        for (int b = 0; b < 2; ++b)
            #pragma unroll
            for (int e = 0; e < 16; ++e) acc[a][b][e] = 0;

    i32x4 fa[2][2], fb[2][2];   // [reg set][tile]

#define STAGE(KC, BUF)                                                         \
    __builtin_amdgcn_global_load_lds(GLOBAL_AS(gsrcA + (size_t)(KC) * 1024),   \
                                     LDS_AS(&lds[BUF][ldsA]), 16, 0, 0);       \
    __builtin_amdgcn_global_load_lds(GLOBAL_AS(gsrcB + (size_t)(KC) * 1024),   \
                                     LDS_AS(&lds[BUF][ldsB]), 16, 0, 0);

#define PF(SET, BUF)                                                           \
    fa[SET][0] = *(const i32x4*)&lds[BUF][aT0 + alof];                         \
    fa[SET][1] = *(const i32x4*)&lds[BUF][aT0 + 1024 + alof];                  \
    fb[SET][0] = *(const i32x4*)&lds[BUF][bT0 + alof];                         \
    fb[SET][1] = *(const i32x4*)&lds[BUF][bT0 + 1024 + alof];

#define MFMA4(SET)                                                             \
    acc[0][0] = __builtin_amdgcn_mfma_i32_32x32x32_i8(fa[SET][0], fb[SET][0], acc[0][0], 0, 0, 0); \
    acc[0][1] = __builtin_amdgcn_mfma_i32_32x32x32_i8(fa[SET][0], fb[SET][1], acc[0][1], 0, 0, 0); \
    acc[1][0] = __builtin_amdgcn_mfma_i32_32x32x32_i8(fa[SET][1], fb[SET][0], acc[1][0], 0, 0, 0); \
    acc[1][1] = __builtin_amdgcn_mfma_i32_32x32x32_i8(fa[SET][1], fb[SET][1], acc[1][1], 0, 0, 0);

#define WAITV(N) asm volatile("s_waitcnt vmcnt(" #N ")" ::: "memory")

    // prologue: stage chunks 0..3 into bufs 0..3 (8 glds outstanding/wave)
    STAGE(0, 0); STAGE(1, 1); STAGE(2, 2); STAGE(3, 3);
    WAITV(4);                                // chunks 0,1 resident
    __builtin_amdgcn_s_barrier();
    PF(0, 0);                                // chunk 0 fragments

    int cbuf = 0;                            // buffer of chunk kc (kc % 5)
    for (int kc = 0; kc < 28; ++kc) {
        const int sb = (cbuf >= 1) ? cbuf - 1 : 4;    // (kc+4)%5: held kc-1
        STAGE(kc + 4, sb);
        const int nb = (cbuf == 4) ? 0 : cbuf + 1;    // buffer of chunk kc+1
        PF((kc + 1) & 1, nb);                // prefetch chunk kc+1 (certified)
        MFMA4(kc & 1);                       // chunk kc
        WAITV(4);                            // certifies chunks kc+1, kc+2
        __builtin_amdgcn_s_barrier();
        cbuf = nb;
    }
    // peeled tail: chunks 28..31 in bufs 3,4,0,1 (chunk 28 already in set 0)
    PF(1, 4);                                // chunk 29 (certified at barrier 27)
    MFMA4(0);                                // chunk 28
    WAITV(2); __builtin_amdgcn_s_barrier();  // certifies chunk 30
    PF(0, 0);                                // chunk 30
    MFMA4(1);                                // chunk 29
    WAITV(0); __builtin_amdgcn_s_barrier();  // certifies chunk 31
    PF(1, 1);                                // chunk 31
    MFMA4(0);                                // chunk 30
    MFMA4(1);                                // chunk 31

    // epilogue: exp(acc*10/16129), diag-block triangle mask, row/col partials.
    // C layout (32x32, shape-determined, dtype-independent): col = lane&31,
    // row = (reg&3) + 8*(reg>>2) + 4*(lane>>5)
    __syncthreads();                         // K-loop fully done; lds reusable
    float* rpart = (float*)&lds[0][0];
    float* cpart = (float*)&lds[0][512];
    if (t < 128) { rpart[t] = 0.0f; cpart[t] = 0.0f; }
    __syncthreads();
    const int half = lane >> 5, col = lane & 31;
    float csum[2] = {0.0f, 0.0f};
    #pragma unroll
    for (int ti = 0; ti < 2; ++ti) {
        float rs[16];
        #pragma unroll
        for (int reg = 0; reg < 16; ++reg) rs[reg] = 0.0f;
        #pragma unroll
        for (int tj = 0; tj < 2; ++tj) {
            const int lj = qj * 64 + tj * 32 + col;
            #pragma unroll
            for (int reg = 0; reg < 16; ++reg) {
                const int li = qi * 64 + ti * 32 + (reg & 3) + 8 * (reg >> 2) + 4 * half;
                float e = __expf((float)acc[ti][tj][reg] * INVT_I8);
                if (diag && li >= lj) e = 0.0f;      // bi<bj blocks: always li<lj globally
                rs[reg] += e;
                csum[tj] += e;
            }
        }
        #pragma unroll
        for (int reg = 0; reg < 16; ++reg) {
            float v = rs[reg];
            v += __shfl_xor(v, 1); v += __shfl_xor(v, 2); v += __shfl_xor(v, 4);
            v += __shfl_xor(v, 8); v += __shfl_xor(v, 16);
            if (col == 0)
                atomicAdd(&rpart[qi * 64 + ti * 32 + (reg & 3) + 8 * (reg >> 2) + 4 * half], v);
        }
    }
    #pragma unroll
    for (int tj = 0; tj < 2; ++tj) {
        float v = csum[tj];
        v += __shfl_xor(v, 32);
        if (half == 0) atomicAdd(&cpart[qj * 64 + tj * 32 + col], v);
    }
    __syncthreads();
    if (t < 128) atomicAdd(&rowsum[bi * 128 + t], rpart[t]);
    else         atomicAdd(&rowsum[bj * 128 + (t - 128)], cpart[t - 128]);
}

// ---------------------------------------------------------------------------
// rowsum == sum_neg (diag + lower triangle excluded in gram)
__global__ __launch_bounds__(256) void final2_kernel(const float* __restrict__ rowsum,
                                                     float* __restrict__ out) {
    __shared__ float red[4];
    const int t = threadIdx.x;
    const int i = blockIdx.x * 256 + t;
    float v = logf(rowsum[i] * (1.0f / (float)(C - 1)));
    #pragma unroll
    for (int off = 32; off > 0; off >>= 1) v += __shfl_down(v, off);
    if ((t & 63) == 0) red[t >> 6] = v;
    __syncthreads();
    if (t == 0)
        atomicAdd(out, (red[0] + red[1] + red[2] + red[3]) * (1.0f / (float)C));
}

// ---------------------------------------------------------------------------
extern "C" void kernel_launch(void* const* d_in, const int* in_sizes, int n_in,
                              void* d_out, int out_size, void* d_ws, size_t ws_size,
                              hipStream_t stream) {
    const float* feat = (const float*)d_in[0];
    const int* labels = (const int*)d_in[1];
    const float* protos = (const float*)d_in[2];
    float* out = (float*)d_out;
    float* rowsum = (float*)d_ws;               // 32 KB
    u8* P8 = (u8*)((char*)d_ws + 32768);        // 8 MiB packed int8 protos

    ema_split_kernel<<<C / 16, 256, 0, stream>>>(feat, labels, protos, P8, rowsum, out);
    gram8_kernel<<<2080, 256, 0, stream>>>(P8, rowsum);
    final2_kernel<<<C / 256, 256, 0, stream>>>(rowsum, out);
}